// Round 3
// baseline (319.648 us; speedup 1.0000x reference)
//
#include <hip/hip_runtime.h>
#include <hip/hip_bf16.h>

#define B_N  4096
#define K_D  1024
#define TILE 128
#define BK   64
#define PADK (BK + 8)          // 72 elems = 144 B row stride -> conflict-free reads
#define NBLK ((B_N / TILE) * (B_N / TILE))

typedef __bf16 bf16x8 __attribute__((ext_vector_type(8)));
typedef float  f32x4  __attribute__((ext_vector_type(4)));

// round-to-nearest-even float -> bf16 bits
__device__ __forceinline__ unsigned short f2bf(float x) {
    union { float f; unsigned int u; } v; v.f = x;
    unsigned int r = v.u + 0x7fffu + ((v.u >> 16) & 1u);
    return (unsigned short)(r >> 16);
}

// One block per row: L2 norm -> bf16 normalized row. Also zeroes reduction scratch.
__global__ void normalize_bf16(const float* __restrict__ f, unsigned short* __restrict__ fnb,
                               float* __restrict__ rowsum, float* __restrict__ possum,
                               int* __restrict__ counter) {
    const int row = blockIdx.x;
    const int tid = threadIdx.x;
    float4 v = ((const float4*)(f + (size_t)row * K_D))[tid];
    float s = v.x * v.x + v.y * v.y + v.z * v.z + v.w * v.w;
#pragma unroll
    for (int m = 1; m < 64; m <<= 1) s += __shfl_xor(s, m, 64);
    __shared__ float wsum[4];
    if ((tid & 63) == 0) wsum[tid >> 6] = s;
    __syncthreads();
    float tot = wsum[0] + wsum[1] + wsum[2] + wsum[3];
    float scale = 1.0f / fmaxf(sqrtf(tot), 1e-12f);
    ushort4 o;
    o.x = f2bf(v.x * scale); o.y = f2bf(v.y * scale);
    o.z = f2bf(v.z * scale); o.w = f2bf(v.w * scale);
    ((ushort4*)(fnb + (size_t)row * K_D))[tid] = o;
    if (tid == 0) {
        rowsum[row] = 0.0f;
        if (row == 0) { *possum = 0.0f; *counter = 0; }
    }
}

// 128x128 tile of sim = fn*fn^T. 4 waves 2x2; each wave a 64x64 quadrant
// (4x4 frags of 16x16x32 bf16 MFMA).
// Staging: coalesced global_load_dwordx4 -> registers -> ds_write_b128 into a
// PADK(=72)-strided LDS layout. Writes hit each 4-bank group exactly 8x (b128
// floor); fragment reads land on bank-quad (l15+4*quad)&7 = uniform -> zero
// conflicts. Next iteration's global loads are issued BEFORE the MFMA section
// (prefetch hidden behind MFMA+ds_read; vmcnt wait lands at next ds_write).
__global__ void gemm_exp_reduce(const unsigned short* __restrict__ fnb,
                                const int* __restrict__ labels,
                                float* __restrict__ rowsum,
                                float* __restrict__ possum,
                                int* __restrict__ counter,
                                float* __restrict__ out) {
    __shared__ __align__(16) unsigned short As[TILE * PADK]; // 18432 B
    __shared__ __align__(16) unsigned short Bs[TILE * PADK]; // 18432 B
    __shared__ int   rlab[TILE];
    __shared__ int   clab[TILE];
    __shared__ float fred[4];
    __shared__ int   isLast;

    const int bi = blockIdx.y, bj = blockIdx.x;
    const int row0 = bi * TILE, col0 = bj * TILE;
    const int tid  = threadIdx.x;
    const int lane = tid & 63, wave = tid >> 6;
    const int wr = wave >> 1, wc = wave & 1;
    const int quad = lane >> 4, l15 = lane & 15;

    if (tid < TILE) rlab[tid] = labels[row0 + tid];
    else            clab[tid - TILE] = labels[col0 + tid - TILE];

    // staging coordinates for this thread (4 chunks of 16 B per tile per iter)
    const int sr[4] = { (0*256+tid) >> 3, (1*256+tid) >> 3,
                        (2*256+tid) >> 3, (3*256+tid) >> 3 };
    const int sg    = (tid & 7) * 8;   // element offset within row (c&7 == tid&7)
    const unsigned short* gA = fnb + (size_t)row0 * K_D + sg;
    const unsigned short* gB = fnb + (size_t)col0 * K_D + sg;

    f32x4 acc[4][4];
#pragma unroll
    for (int i = 0; i < 4; ++i)
#pragma unroll
        for (int j = 0; j < 4; ++j) {
            f32x4 z = {0.f, 0.f, 0.f, 0.f};
            acc[i][j] = z;
        }

    int4 ra[4], rb[4];
    // prologue: load tile k0=0
#pragma unroll
    for (int it = 0; it < 4; ++it) {
        ra[it] = *(const int4*)(gA + (size_t)sr[it] * K_D);
        rb[it] = *(const int4*)(gB + (size_t)sr[it] * K_D);
    }

    for (int k0 = 0; k0 < K_D; k0 += BK) {
        __syncthreads();   // previous iteration's reads done before overwrite
#pragma unroll
        for (int it = 0; it < 4; ++it) {
            *(int4*)&As[sr[it] * PADK + sg] = ra[it];
            *(int4*)&Bs[sr[it] * PADK + sg] = rb[it];
        }
        __syncthreads();

        if (k0 + BK < K_D) {   // prefetch next tile; hidden behind MFMA below
#pragma unroll
            for (int it = 0; it < 4; ++it) {
                ra[it] = *(const int4*)(gA + (size_t)sr[it] * K_D + k0 + BK);
                rb[it] = *(const int4*)(gB + (size_t)sr[it] * K_D + k0 + BK);
            }
        }

#pragma unroll
        for (int ks = 0; ks < 2; ++ks) {   // kk = ks*32
            bf16x8 af[4], bf[4];
#pragma unroll
            for (int fr = 0; fr < 4; ++fr)
                af[fr] = *(const bf16x8*)&As[(wr * 64 + fr * 16 + l15) * PADK
                                             + ks * 32 + quad * 8];
#pragma unroll
            for (int fc = 0; fc < 4; ++fc)
                bf[fc] = *(const bf16x8*)&Bs[(wc * 64 + fc * 16 + l15) * PADK
                                             + ks * 32 + quad * 8];
#pragma unroll
            for (int fr = 0; fr < 4; ++fr)
#pragma unroll
                for (int fc = 0; fc < 4; ++fc)
                    acc[fr][fc] = __builtin_amdgcn_mfma_f32_16x16x32_bf16(
                        af[fr], bf[fc], acc[fr][fc], 0, 0, 0);
        }
    }

    // Epilogue. C/D layout (m89/m91): col = lane&15, row = quad*4 + reg.
    const float ESC = 14.426950408889634f;   // 10/ln2 : exp(10x)=exp2(x*ESC)
    float pospart = 0.0f;
#pragma unroll
    for (int fr = 0; fr < 4; ++fr) {
        float rp[4] = {0.f, 0.f, 0.f, 0.f};
#pragma unroll
        for (int fc = 0; fc < 4; ++fc) {
            int c    = wc * 64 + fc * 16 + l15;
            int gcol = col0 + c;
            int cl   = clab[c];
#pragma unroll
            for (int r = 0; r < 4; ++r) {
                int rr   = wr * 64 + fr * 16 + quad * 4 + r;
                int grow = row0 + rr;
                float e  = (grow == gcol) ? 0.0f : exp2f(acc[fr][fc][r] * ESC);
                rp[r] += e;
                pospart += (rlab[rr] == cl) ? e : 0.0f;
            }
        }
#pragma unroll
        for (int r = 0; r < 4; ++r) {
            float v = rp[r];
            v += __shfl_xor(v, 1, 64);
            v += __shfl_xor(v, 2, 64);
            v += __shfl_xor(v, 4, 64);
            v += __shfl_xor(v, 8, 64);
            if (l15 == 0)
                atomicAdd(&rowsum[row0 + wr * 64 + fr * 16 + quad * 4 + r], v);
        }
    }
#pragma unroll
    for (int m = 1; m < 64; m <<= 1) pospart += __shfl_xor(pospart, m, 64);
    if (lane == 0) atomicAdd(possum, pospart);

    // ---- last-block finalize ----
    __threadfence();
    if (tid == 0) {
        int old = atomicAdd(counter, 1);
        isLast = (old == NBLK - 1);
    }
    __syncthreads();
    if (isLast) {
        float s = 0.f;
        for (int i = tid; i < B_N; i += 256) {
            float rs = __hip_atomic_load(&rowsum[i], __ATOMIC_RELAXED,
                                         __HIP_MEMORY_SCOPE_AGENT);
            s += __logf(rs);
        }
#pragma unroll
        for (int m = 1; m < 64; m <<= 1) s += __shfl_xor(s, m, 64);
        if (lane == 0) fred[wave] = s;
        __syncthreads();
        if (tid == 0) {
            float tot = fred[0] + fred[1] + fred[2] + fred[3];
            float ps  = __hip_atomic_load(possum, __ATOMIC_RELAXED,
                                          __HIP_MEMORY_SCOPE_AGENT);
            out[0] = tot / (float)B_N - __logf(ps);
        }
    }
}

extern "C" void kernel_launch(void* const* d_in, const int* in_sizes, int n_in,
                              void* d_out, int out_size, void* d_ws, size_t ws_size,
                              hipStream_t stream) {
    const float* features = (const float*)d_in[0];
    const int*   targets  = (const int*)d_in[1];
    float*       out      = (float*)d_out;

    // ws: [bf16 fn: 8 MB][rowsum: 4096 f32][possum: 1 f32][counter: 1 int]
    unsigned short* fnb     = (unsigned short*)d_ws;
    float*          rowsum  = (float*)((char*)d_ws + (size_t)B_N * K_D * sizeof(unsigned short));
    float*          possum  = rowsum + B_N;
    int*            counter = (int*)(possum + 1);

    normalize_bf16<<<B_N, 256, 0, stream>>>(features, fnb, rowsum, possum, counter);
    dim3 grid(B_N / TILE, B_N / TILE);
    gemm_exp_reduce<<<grid, 256, 0, stream>>>(fnb, targets, rowsum, possum, counter, out);
}

// Round 4
// 314.635 us; speedup vs baseline: 1.0159x; 1.0159x over previous
//
#include <hip/hip_runtime.h>
#include <hip/hip_bf16.h>

#define B_N  4096
#define K_D  1024
#define TILE 128
#define BK   64
#define PADK (BK + 8)          // 72 elems = 144 B row stride -> conflict-free reads
#define NBLK ((B_N / TILE) * (B_N / TILE))

typedef __bf16 bf16x8 __attribute__((ext_vector_type(8)));
typedef float  f32x4  __attribute__((ext_vector_type(4)));

// round-to-nearest-even float -> bf16 bits
__device__ __forceinline__ unsigned short f2bf(float x) {
    union { float f; unsigned int u; } v; v.f = x;
    unsigned int r = v.u + 0x7fffu + ((v.u >> 16) & 1u);
    return (unsigned short)(r >> 16);
}

// One block per row: L2 norm -> bf16 normalized row. Also zeroes reduction scratch.
__global__ void normalize_bf16(const float* __restrict__ f, unsigned short* __restrict__ fnb,
                               float* __restrict__ rowsum, float* __restrict__ possum,
                               int* __restrict__ counter) {
    const int row = blockIdx.x;
    const int tid = threadIdx.x;
    float4 v = ((const float4*)(f + (size_t)row * K_D))[tid];
    float s = v.x * v.x + v.y * v.y + v.z * v.z + v.w * v.w;
#pragma unroll
    for (int m = 1; m < 64; m <<= 1) s += __shfl_xor(s, m, 64);
    __shared__ float wsum[4];
    if ((tid & 63) == 0) wsum[tid >> 6] = s;
    __syncthreads();
    float tot = wsum[0] + wsum[1] + wsum[2] + wsum[3];
    float scale = 1.0f / fmaxf(sqrtf(tot), 1e-12f);
    ushort4 o;
    o.x = f2bf(v.x * scale); o.y = f2bf(v.y * scale);
    o.z = f2bf(v.z * scale); o.w = f2bf(v.w * scale);
    ((ushort4*)(fnb + (size_t)row * K_D))[tid] = o;
    if (tid == 0) {
        rowsum[row] = 0.0f;
        if (row == 0) { *possum = 0.0f; *counter = 0; }
    }
}

// 128x128 tile of sim = fn*fn^T. 4 waves 2x2; each wave a 64x64 quadrant
// (4x4 frags of 16x16x32 bf16 MFMA).
// Staging: coalesced global_load_dwordx4 -> registers -> ds_write_b128 into a
// PADK(=72)-strided LDS layout (conflict-free frag reads). Next iteration's
// global loads issue before the MFMA section (prefetch hidden behind MFMA).
// __launch_bounds__(256,3): ~170-reg cap holds acc(64 AGPR)+prefetch(32 VGPR)
// without scratch spill (R3 at the default 64-cap spilled 773 MB/launch).
__global__ void __launch_bounds__(256, 3)
gemm_exp_reduce(const unsigned short* __restrict__ fnb,
                const int* __restrict__ labels,
                float* __restrict__ rowsum,
                float* __restrict__ possum,
                int* __restrict__ counter,
                float* __restrict__ out) {
    __shared__ __align__(16) unsigned short As[TILE * PADK]; // 18432 B
    __shared__ __align__(16) unsigned short Bs[TILE * PADK]; // 18432 B
    __shared__ int   rlab[TILE];
    __shared__ int   clab[TILE];
    __shared__ float fred[4];
    __shared__ int   isLast;

    const int bi = blockIdx.y, bj = blockIdx.x;
    const int row0 = bi * TILE, col0 = bj * TILE;
    const int tid  = threadIdx.x;
    const int lane = tid & 63, wave = tid >> 6;
    const int wr = wave >> 1, wc = wave & 1;
    const int quad = lane >> 4, l15 = lane & 15;

    if (tid < TILE) rlab[tid] = labels[row0 + tid];
    else            clab[tid - TILE] = labels[col0 + tid - TILE];

    // staging coordinates (4 chunks of 16 B per tile per iter)
    const int r0t = tid >> 3;          // sr[it] = it*32 + r0t
    const int sg  = (tid & 7) * 8;
    const unsigned short* gA = fnb + (size_t)row0 * K_D + (size_t)r0t * K_D + sg;
    const unsigned short* gB = fnb + (size_t)col0 * K_D + (size_t)r0t * K_D + sg;

    f32x4 acc[4][4];
#pragma unroll
    for (int i = 0; i < 4; ++i)
#pragma unroll
        for (int j = 0; j < 4; ++j) {
            f32x4 z = {0.f, 0.f, 0.f, 0.f};
            acc[i][j] = z;
        }

    int4 ra[4], rb[4];
#pragma unroll
    for (int it = 0; it < 4; ++it) {
        ra[it] = *(const int4*)(gA + (size_t)(it * 32) * K_D);
        rb[it] = *(const int4*)(gB + (size_t)(it * 32) * K_D);
    }

    for (int k0 = 0; k0 < K_D; k0 += BK) {
        __syncthreads();   // previous iteration's reads done before overwrite
#pragma unroll
        for (int it = 0; it < 4; ++it) {
            *(int4*)&As[(it * 32 + r0t) * PADK + sg] = ra[it];
            *(int4*)&Bs[(it * 32 + r0t) * PADK + sg] = rb[it];
        }
        __syncthreads();

        if (k0 + BK < K_D) {   // prefetch next tile; hidden behind MFMA below
#pragma unroll
            for (int it = 0; it < 4; ++it) {
                ra[it] = *(const int4*)(gA + (size_t)(it * 32) * K_D + k0 + BK);
                rb[it] = *(const int4*)(gB + (size_t)(it * 32) * K_D + k0 + BK);
            }
        }

#pragma unroll
        for (int ks = 0; ks < 2; ++ks) {   // kk = ks*32
            bf16x8 af[4], bf[4];
#pragma unroll
            for (int fr = 0; fr < 4; ++fr)
                af[fr] = *(const bf16x8*)&As[(wr * 64 + fr * 16 + l15) * PADK
                                             + ks * 32 + quad * 8];
#pragma unroll
            for (int fc = 0; fc < 4; ++fc)
                bf[fc] = *(const bf16x8*)&Bs[(wc * 64 + fc * 16 + l15) * PADK
                                             + ks * 32 + quad * 8];
#pragma unroll
            for (int fr = 0; fr < 4; ++fr)
#pragma unroll
                for (int fc = 0; fc < 4; ++fc)
                    acc[fr][fc] = __builtin_amdgcn_mfma_f32_16x16x32_bf16(
                        af[fr], bf[fc], acc[fr][fc], 0, 0, 0);
        }
    }

    // Epilogue. C/D layout (m89/m91): col = lane&15, row = quad*4 + reg.
    const float ESC = 14.426950408889634f;   // 10/ln2 : exp(10x)=exp2(x*ESC)
    float pospart = 0.0f;
#pragma unroll
    for (int fr = 0; fr < 4; ++fr) {
        float rp[4] = {0.f, 0.f, 0.f, 0.f};
#pragma unroll
        for (int fc = 0; fc < 4; ++fc) {
            int c    = wc * 64 + fc * 16 + l15;
            int gcol = col0 + c;
            int cl   = clab[c];
#pragma unroll
            for (int r = 0; r < 4; ++r) {
                int rr   = wr * 64 + fr * 16 + quad * 4 + r;
                int grow = row0 + rr;
                float e  = (grow == gcol) ? 0.0f : exp2f(acc[fr][fc][r] * ESC);
                rp[r] += e;
                pospart += (rlab[rr] == cl) ? e : 0.0f;
            }
        }
#pragma unroll
        for (int r = 0; r < 4; ++r) {
            float v = rp[r];
            v += __shfl_xor(v, 1, 64);
            v += __shfl_xor(v, 2, 64);
            v += __shfl_xor(v, 4, 64);
            v += __shfl_xor(v, 8, 64);
            if (l15 == 0)
                atomicAdd(&rowsum[row0 + wr * 64 + fr * 16 + quad * 4 + r], v);
        }
    }
#pragma unroll
    for (int m = 1; m < 64; m <<= 1) pospart += __shfl_xor(pospart, m, 64);
    if (lane == 0) atomicAdd(possum, pospart);

    // ---- last-block finalize ----
    __threadfence();
    if (tid == 0) {
        int old = atomicAdd(counter, 1);
        isLast = (old == NBLK - 1);
    }
    __syncthreads();
    if (isLast) {
        float s = 0.f;
        for (int i = tid; i < B_N; i += 256) {
            float rs = __hip_atomic_load(&rowsum[i], __ATOMIC_RELAXED,
                                         __HIP_MEMORY_SCOPE_AGENT);
            s += __logf(rs);
        }
#pragma unroll
        for (int m = 1; m < 64; m <<= 1) s += __shfl_xor(s, m, 64);
        if (lane == 0) fred[wave] = s;
        __syncthreads();
        if (tid == 0) {
            float tot = fred[0] + fred[1] + fred[2] + fred[3];
            float ps  = __hip_atomic_load(possum, __ATOMIC_RELAXED,
                                          __HIP_MEMORY_SCOPE_AGENT);
            out[0] = tot / (float)B_N - __logf(ps);
        }
    }
}

extern "C" void kernel_launch(void* const* d_in, const int* in_sizes, int n_in,
                              void* d_out, int out_size, void* d_ws, size_t ws_size,
                              hipStream_t stream) {
    const float* features = (const float*)d_in[0];
    const int*   targets  = (const int*)d_in[1];
    float*       out      = (float*)d_out;

    // ws: [bf16 fn: 8 MB][rowsum: 4096 f32][possum: 1 f32][counter: 1 int]
    unsigned short* fnb     = (unsigned short*)d_ws;
    float*          rowsum  = (float*)((char*)d_ws + (size_t)B_N * K_D * sizeof(unsigned short));
    float*          possum  = rowsum + B_N;
    int*            counter = (int*)(possum + 1);

    normalize_bf16<<<B_N, 256, 0, stream>>>(features, fnb, rowsum, possum, counter);
    dim3 grid(B_N / TILE, B_N / TILE);
    gemm_exp_reduce<<<grid, 256, 0, stream>>>(fnb, targets, rowsum, possum, counter, out);
}

// Round 5
// 144.040 us; speedup vs baseline: 2.2192x; 2.1844x over previous
//
#include <hip/hip_runtime.h>
#include <hip/hip_bf16.h>

#define B_N   4096
#define K_D   1024
#define KP    1040              // padded global row stride (elems); 2080 B, 16B-aligned
#define TILE  128
#define BK    64
#define PADK  72                // LDS row stride (elems) = 144 B -> conflict-free frag reads
#define NT    (B_N / TILE)      // 32 tile-rows
#define NTRI  (NT * (NT + 1) / 2)   // 528 upper-triangle blocks

typedef __bf16 bf16x8 __attribute__((ext_vector_type(8)));
typedef float  f32x4  __attribute__((ext_vector_type(4)));

// round-to-nearest-even float -> bf16 bits
__device__ __forceinline__ unsigned short f2bf(float x) {
    union { float f; unsigned int u; } v; v.f = x;
    unsigned int r = v.u + 0x7fffu + ((v.u >> 16) & 1u);
    return (unsigned short)(r >> 16);
}

// One block per row: L2 norm -> bf16 normalized row at padded stride KP.
// Also zeroes the reduction scratch (rowsum/possum/counter).
__global__ void normalize_bf16(const float* __restrict__ f, unsigned short* __restrict__ fnb,
                               float* __restrict__ rowsum, float* __restrict__ possum,
                               int* __restrict__ counter) {
    const int row = blockIdx.x;
    const int tid = threadIdx.x;
    float4 v = ((const float4*)(f + (size_t)row * K_D))[tid];
    float s = v.x * v.x + v.y * v.y + v.z * v.z + v.w * v.w;
#pragma unroll
    for (int m = 1; m < 64; m <<= 1) s += __shfl_xor(s, m, 64);
    __shared__ float wsum[4];
    if ((tid & 63) == 0) wsum[tid >> 6] = s;
    __syncthreads();
    float tot = wsum[0] + wsum[1] + wsum[2] + wsum[3];
    float scale = 1.0f / fmaxf(sqrtf(tot), 1e-12f);
    ushort4 o;
    o.x = f2bf(v.x * scale); o.y = f2bf(v.y * scale);
    o.z = f2bf(v.z * scale); o.w = f2bf(v.w * scale);
    ((ushort4*)(fnb + (size_t)row * KP))[tid] = o;
    if (tid == 0) {
        rowsum[row] = 0.0f;
        if (row == 0) { *possum = 0.0f; *counter = 0; }
    }
}

// Upper-triangle 128x128 tiles of sim = fn*fn^T (528 blocks). 4 waves 2x2;
// each wave a 64x64 quadrant (4x4 frags of 16x16x32 bf16 MFMA).
// Staging: global_load_lds width=16, 9 chunks per row (64 data + 8 pad elems)
// from the KP-padded global buffer -> LDS rows at 144 B stride. Lane order is
// linear (hardware requirement) and sources ascend (coalescing preserved);
// fragment reads hit bank-group 4*((row+quad)&7) -> uniform 8 lanes/bank =
// conflict-free. Off-diagonal blocks mirror via symmetry: column-sums go to
// rowsum[col0+c], pospart doubles. Last block finalizes the loss.
__global__ void gemm_exp_reduce(const unsigned short* __restrict__ fnb,
                                const int* __restrict__ labels,
                                float* __restrict__ rowsum,
                                float* __restrict__ possum,
                                int* __restrict__ counter,
                                float* __restrict__ out) {
    __shared__ __align__(16) unsigned short As[TILE * PADK]; // 18432 B
    __shared__ __align__(16) unsigned short Bs[TILE * PADK]; // 18432 B
    __shared__ int   rlab[TILE];
    __shared__ int   clab[TILE];
    __shared__ float fred[4];
    __shared__ int   isLast;

    // linear block -> (bi, bj) with bi <= bj (upper triangle incl. diagonal)
    int b = blockIdx.x, bi = 0;
    while (b >= NT - bi) { b -= NT - bi; ++bi; }   // scalar, <=32 iters
    const int bj = bi + b;
    const bool offdiag = (bi != bj);

    const int row0 = bi * TILE, col0 = bj * TILE;
    const int tid  = threadIdx.x;
    const int lane = tid & 63, wave = tid >> 6;
    const int wr = wave >> 1, wc = wave & 1;
    const int quad = lane >> 4, l15 = lane & 15;

    if (tid < TILE) rlab[tid] = labels[row0 + tid];
    else            clab[tid - TILE] = labels[col0 + tid - TILE];

    f32x4 acc[4][4];
#pragma unroll
    for (int i = 0; i < 4; ++i)
#pragma unroll
        for (int j = 0; j < 4; ++j) {
            f32x4 z = {0.f, 0.f, 0.f, 0.f};
            acc[i][j] = z;
        }

    const unsigned short* gA = fnb + (size_t)row0 * KP;
    const unsigned short* gB = fnb + (size_t)col0 * KP;

    for (int k0 = 0; k0 < K_D; k0 += BK) {
        // 1152 chunks of 16 B per tile: chunk c -> LDS row c/9, slot c%9.
        // slot 8 loads pad elems [k0+64, k0+72) (never read by MFMA).
#pragma unroll
        for (int it = 0; it < 4; ++it) {
            int c    = it * 256 + tid;
            int r    = c / 9;
            int slot = c - r * 9;
            __builtin_amdgcn_global_load_lds(
                (const unsigned int*)(gA + (size_t)r * KP + k0 + slot * 8),
                (unsigned int*)&As[c * 8], 16, 0, 0);
            __builtin_amdgcn_global_load_lds(
                (const unsigned int*)(gB + (size_t)r * KP + k0 + slot * 8),
                (unsigned int*)&Bs[c * 8], 16, 0, 0);
        }
        if (tid < 128) {          // tail: chunks 1024..1151 (waves 0,1 fully active)
            int c    = 1024 + tid;
            int r    = c / 9;
            int slot = c - r * 9;
            __builtin_amdgcn_global_load_lds(
                (const unsigned int*)(gA + (size_t)r * KP + k0 + slot * 8),
                (unsigned int*)&As[c * 8], 16, 0, 0);
            __builtin_amdgcn_global_load_lds(
                (const unsigned int*)(gB + (size_t)r * KP + k0 + slot * 8),
                (unsigned int*)&Bs[c * 8], 16, 0, 0);
        }
        __syncthreads();

#pragma unroll
        for (int ks = 0; ks < 2; ++ks) {   // kk = ks*32
            bf16x8 af[4], bf[4];
#pragma unroll
            for (int fr = 0; fr < 4; ++fr)
                af[fr] = *(const bf16x8*)&As[(wr * 64 + fr * 16 + l15) * PADK
                                             + ks * 32 + quad * 8];
#pragma unroll
            for (int fc = 0; fc < 4; ++fc)
                bf[fc] = *(const bf16x8*)&Bs[(wc * 64 + fc * 16 + l15) * PADK
                                             + ks * 32 + quad * 8];
#pragma unroll
            for (int fr = 0; fr < 4; ++fr)
#pragma unroll
                for (int fc = 0; fc < 4; ++fc)
                    acc[fr][fc] = __builtin_amdgcn_mfma_f32_16x16x32_bf16(
                        af[fr], bf[fc], acc[fr][fc], 0, 0, 0);
        }
        __syncthreads();
    }

    // Epilogue. C/D layout (m89/m91): col = lane&15, row = quad*4 + reg.
    const float ESC = 14.426950408889634f;   // 10/ln2 : exp(10x)=exp2(x*ESC)
    float pospart = 0.0f;
    float cs[4] = {0.f, 0.f, 0.f, 0.f};      // per-fc column partial sums
#pragma unroll
    for (int fr = 0; fr < 4; ++fr) {
        float rp[4] = {0.f, 0.f, 0.f, 0.f};
#pragma unroll
        for (int fc = 0; fc < 4; ++fc) {
            int c    = wc * 64 + fc * 16 + l15;
            int gcol = col0 + c;
            int cl   = clab[c];
#pragma unroll
            for (int r = 0; r < 4; ++r) {
                int rr   = wr * 64 + fr * 16 + quad * 4 + r;
                int grow = row0 + rr;
                float e  = (grow == gcol) ? 0.0f : exp2f(acc[fr][fc][r] * ESC);
                rp[r] += e;
                cs[fc] += e;
                pospart += (rlab[rr] == cl) ? e : 0.0f;
            }
        }
#pragma unroll
        for (int r = 0; r < 4; ++r) {
            float v = rp[r];
            v += __shfl_xor(v, 1, 64);
            v += __shfl_xor(v, 2, 64);
            v += __shfl_xor(v, 4, 64);
            v += __shfl_xor(v, 8, 64);
            if (l15 == 0)
                atomicAdd(&rowsum[row0 + wr * 64 + fr * 16 + quad * 4 + r], v);
        }
    }
    if (offdiag) {
        // mirror: this tile's column sums are row sums of the (bj,bi) block
#pragma unroll
        for (int fc = 0; fc < 4; ++fc) {
            float v = cs[fc];
            v += __shfl_xor(v, 16, 64);
            v += __shfl_xor(v, 32, 64);
            if (quad == 0)
                atomicAdd(&rowsum[col0 + wc * 64 + fc * 16 + l15], v);
        }
        pospart *= 2.0f;   // (i,j) and (j,i) both in possum, e_ij == e_ji
    }
#pragma unroll
    for (int m = 1; m < 64; m <<= 1) pospart += __shfl_xor(pospart, m, 64);
    if (lane == 0) atomicAdd(possum, pospart);

    // ---- last-block finalize ----
    __threadfence();
    if (tid == 0) {
        int old = atomicAdd(counter, 1);
        isLast = (old == NTRI - 1);
    }
    __syncthreads();
    if (isLast) {
        float s = 0.f;
        for (int i = tid; i < B_N; i += 256) {
            float rs = __hip_atomic_load(&rowsum[i], __ATOMIC_RELAXED,
                                         __HIP_MEMORY_SCOPE_AGENT);
            s += __logf(rs);
        }
#pragma unroll
        for (int m = 1; m < 64; m <<= 1) s += __shfl_xor(s, m, 64);
        if (lane == 0) fred[wave] = s;
        __syncthreads();
        if (tid == 0) {
            float tot = fred[0] + fred[1] + fred[2] + fred[3];
            float ps  = __hip_atomic_load(possum, __ATOMIC_RELAXED,
                                          __HIP_MEMORY_SCOPE_AGENT);
            out[0] = tot / (float)B_N - __logf(ps);
        }
    }
}

extern "C" void kernel_launch(void* const* d_in, const int* in_sizes, int n_in,
                              void* d_out, int out_size, void* d_ws, size_t ws_size,
                              hipStream_t stream) {
    const float* features = (const float*)d_in[0];
    const int*   targets  = (const int*)d_in[1];
    float*       out      = (float*)d_out;

    // ws: [bf16 fn padded: 4096*1040*2 B][rowsum: 4096 f32][possum][counter]
    unsigned short* fnb     = (unsigned short*)d_ws;
    float*          rowsum  = (float*)((char*)d_ws + (size_t)B_N * KP * sizeof(unsigned short));
    float*          possum  = rowsum + B_N;
    int*            counter = (int*)(possum + 1);

    normalize_bf16<<<B_N, 256, 0, stream>>>(features, fnb, rowsum, possum, counter);
    gemm_exp_reduce<<<NTRI, 256, 0, stream>>>(fnb, targets, rowsum, possum, counter, out);
}